// Round 9
// baseline (113.912 us; speedup 1.0000x reference)
//
#include <hip/hip_runtime.h>
#include <math.h>

#define NEXP 8
#define DIN 128
#define ISZ 16
#define TT 8                       // tokens per wave
#define NWAVE 4
#define TOK_PER_BLK (TT * NWAVE)   // 32
#define NTOK (16 * 4096)           // 65536

#define LDS_GY (TOK_PER_BLK * DIN)    // 4096 floats = 16 KB (only LDS user)
#define SMEM_BYTES (LDS_GY * 4)

typedef float f32x4 __attribute__((ext_vector_type(4)));

// ---- pack w1 [e][c][i] into lane-major P ----
// P[c4*512 + lane*8 + m*4 + k] = w1[e][4*c4+k][2*g+m],  lane = e*8+g
__global__ void pack_w1_kernel(const float* __restrict__ w1, float* __restrict__ P) {
    int idx = blockIdx.x * 256 + threadIdx.x;       // 0 .. 16383
    int c4 = idx >> 9;
    int r  = idx & 511;
    int ln = r >> 3;
    int j  = r & 7;
    int m  = j >> 2;
    int k  = j & 3;
    int e  = ln >> 3;
    int g  = ln & 7;
    P[idx] = w1[e * 2048 + (4 * c4 + k) * 16 + (2 * g + m)];
}

__global__ __launch_bounds__(256, 1) __attribute__((amdgpu_num_vgpr(128)))
void moe_fused_kernel(
    const float* __restrict__ x,
    const float* __restrict__ rw,
    const float* __restrict__ P,     // packed w1 in d_ws
    const float* __restrict__ w2,
    float* __restrict__ out_agg,
    float* __restrict__ out_exp)
{
    extern __shared__ float lds[];
    float* gys = lds;                        // [32 tok][128] gelu(y), wave-private

    const int tid  = threadIdx.x;
    const int wave = tid >> 6;
    const int lane = tid & 63;
    const int btok = blockIdx.x * TOK_PER_BLK;
    const int wtok = btok + wave * TT;

    float* gyw = gys + wave * TT * DIN;      // wave-private gy slice (4 KB)

    // ================= GEMM1: y[t][e][i] = x . w1 =================
    // lane -> (e1 = lane>>3, g = lane&7); computes i = 2g, 2g+1 for 8 tokens.
    // x addresses are wave-uniform: force uniformity so the compiler puts the
    // x stream on the SCALAR pipe (s_load), off the VALU/LDS critical path.
    const int e1 = lane >> 3;
    const int g  = lane & 7;

    float y0[TT], y1[TT];
#pragma unroll
    for (int t = 0; t < TT; ++t) { y0[t] = 0.f; y1[t] = 0.f; }

    const float* Pl = P + lane * 8;
    const int xoff = __builtin_amdgcn_readfirstlane(wtok * DIN);
    const float* xu = x + xoff;              // uniform base

#pragma unroll 1
    for (int c4 = 0; c4 < 32; ++c4) {
        f32x4 wa = *(const f32x4*)(Pl + c4 * 512);
        f32x4 wb = *(const f32x4*)(Pl + c4 * 512 + 4);
#pragma unroll
        for (int t = 0; t < TT; ++t) {
            float x0 = xu[t * DIN + c4 * 4 + 0];   // uniform -> s_load
            float x1 = xu[t * DIN + c4 * 4 + 1];
            float x2 = xu[t * DIN + c4 * 4 + 2];
            float x3 = xu[t * DIN + c4 * 4 + 3];
            y0[t] += x0 * wa.x + x1 * wa.y + x2 * wa.z + x3 * wa.w;
            y1[t] += x0 * wb.x + x1 * wb.y + x2 * wb.z + x3 * wb.w;
        }
    }

    // ---- exact GELU -> wave-private LDS slice (same-wave producer/consumer,
    //      no __syncthreads needed) ----
#pragma unroll
    for (int t = 0; t < TT; ++t) {
        float a = y0[t], b = y1[t];
        a = 0.5f * a * (1.f + erff(a * 0.70710678118654752f));
        b = 0.5f * b * (1.f + erff(b * 0.70710678118654752f));
        *(float2*)(gyw + t * DIN + e1 * ISZ + 2 * g) = make_float2(a, b);
    }

    // ================= GEMM2 + weighted agg =================
    // lane -> c4s = (lane&31)*4 channel quad, h = lane>>5 expert parity
    const int c4s = (lane & 31) * 4;
    const int h   = lane >> 5;
    const float* w2h = w2 + h * (ISZ * DIN) + c4s;  // expert e=2k+h -> + k*4096
    const f32x4 vzero = (f32x4)(0.f);

#pragma unroll
    for (int th = 0; th < 2; ++th) {          // two 4-token halves
        f32x4 acc[4], agg[4];
#pragma unroll
        for (int t = 0; t < 4; ++t) { acc[t] = vzero; agg[t] = vzero; }

        // prime chunk 0 (k=0, i4=0): rows 0..3 of expert h
        f32x4 w0  = *(const f32x4*)(w2h + 0);
        f32x4 wv1 = *(const f32x4*)(w2h + 128);
        f32x4 wv2 = *(const f32x4*)(w2h + 256);
        f32x4 wv3 = *(const f32x4*)(w2h + 384);

#pragma unroll 1
        for (int ch = 0; ch < 16; ++ch) {     // (k = ch>>2, i4 = ch&3)
            const int k  = ch >> 2;
            const int i4 = ch & 3;
            const int nch = (ch < 15) ? ch + 1 : 15;   // clamped prefetch
            const float* nb = w2h + (nch >> 2) * 4096 + (nch & 3) * 4 * DIN;
            f32x4 n0 = *(const f32x4*)(nb + 0);
            f32x4 n1 = *(const f32x4*)(nb + 128);
            f32x4 n2 = *(const f32x4*)(nb + 256);
            f32x4 n3 = *(const f32x4*)(nb + 384);

            const int e = 2 * k + h;
#pragma unroll
            for (int t = 0; t < 4; ++t) {
                f32x4 gv = *(const f32x4*)(gyw + (th * 4 + t) * DIN + e * ISZ + i4 * 4);
                acc[t] += w0 * gv.x + wv1 * gv.y + wv2 * gv.z + wv3 * gv.w;
            }

            if (i4 == 3) {   // expert e complete: store + weighted agg + reset
#pragma unroll
                for (int t = 0; t < 4; ++t) {
                    const int gtok = wtok + th * 4 + t;
                    __builtin_nontemporal_store(acc[t],
                        (f32x4*)(out_exp + (size_t)gtok * (NEXP * DIN) + e * DIN + c4s));
                    float r = rw[(size_t)gtok * NEXP + e];   // L1 broadcast
                    agg[t] += r * acc[t];
                    acc[t] = vzero;
                }
            }
            w0 = n0; wv1 = n1; wv2 = n2; wv3 = n3;
        }

        // combine expert parities: lane l (+) lane l^32, then lanes 0..31 write
#pragma unroll
        for (int t = 0; t < 4; ++t) {
            agg[t].x += __shfl_xor(agg[t].x, 32);
            agg[t].y += __shfl_xor(agg[t].y, 32);
            agg[t].z += __shfl_xor(agg[t].z, 32);
            agg[t].w += __shfl_xor(agg[t].w, 32);
        }
        if (h == 0) {
#pragma unroll
            for (int t = 0; t < 4; ++t) {
                const int gtok = wtok + th * 4 + t;
                __builtin_nontemporal_store(agg[t],
                    (f32x4*)(out_agg + (size_t)gtok * DIN + c4s));
            }
        }
    }
}

extern "C" void kernel_launch(void* const* d_in, const int* in_sizes, int n_in,
                              void* d_out, int out_size, void* d_ws, size_t ws_size,
                              hipStream_t stream) {
    const float* x  = (const float*)d_in[0];
    const float* rw = (const float*)d_in[1];
    const float* w1 = (const float*)d_in[2];
    const float* w2 = (const float*)d_in[3];

    float* out_agg = (float*)d_out;                  // [NTOK][128]
    float* out_exp = out_agg + (size_t)NTOK * DIN;   // [NTOK][8][128]
    float* P = (float*)d_ws;                         // 64 KB packed w1

    pack_w1_kernel<<<dim3(64), dim3(256), 0, stream>>>(w1, P);

    dim3 grid(NTOK / TOK_PER_BLK);   // 2048
    dim3 block(256);
    moe_fused_kernel<<<grid, block, SMEM_BYTES, stream>>>(
        x, rw, P, w2, out_agg, out_exp);
}